// Round 1
// baseline (614.299 us; speedup 1.0000x reference)
//
#include <hip/hip_runtime.h>
#include <hip/hip_bf16.h>
#include <math.h>

// Problem constants (S, B, D_IN, D_SRC, D_ALIGN = 2048, 64, 512, 512, 512)
#define S_LEN 2048
#define BATCH 64
#define DDIM 512

typedef __attribute__((ext_vector_type(8))) short bf16x8;
typedef __attribute__((ext_vector_type(8))) unsigned short u16x8;
typedef __attribute__((ext_vector_type(4))) float f32x4;

__device__ __forceinline__ unsigned short f2bf(float f) {
  // round-to-nearest-even fp32 -> bf16
  unsigned int u = __float_as_uint(f);
  u += 0x7fffu + ((u >> 16) & 1u);
  return (unsigned short)(u >> 16);
}

// ---------------------------------------------------------------------------
// prep: W1b[a][d] = bf16(W1[a][512+d]);  uprime[b][a] = b1[a] + W1[a,:512].input[b]
// grid: 512 blocks (one per a), 256 threads
// ---------------------------------------------------------------------------
__global__ __launch_bounds__(256) void prep_kernel(
    const float* __restrict__ W1, const float* __restrict__ b1,
    const float* __restrict__ input, unsigned short* __restrict__ W1b,
    float* __restrict__ uprime) {
  __shared__ float w1row[1024];
  const int a = blockIdx.x;
  const int t = threadIdx.x;
  float4 v = *(const float4*)(W1 + a * 1024 + t * 4);
  *(float4*)(w1row + t * 4) = v;
  if (t >= 128) {  // cols 512..1023 -> bf16 B matrix [a][d2]
    ushort4 u;
    u.x = f2bf(v.x); u.y = f2bf(v.y); u.z = f2bf(v.z); u.w = f2bf(v.w);
    *(ushort4*)(W1b + a * 512 + (t * 4 - 512)) = u;
  }
  __syncthreads();
  if (t < BATCH) {
    const float4* inp = (const float4*)(input + t * 512);
    const float4* wr = (const float4*)w1row;
    float acc = b1[a];
#pragma unroll 4
    for (int d = 0; d < 128; ++d) {
      float4 x = inp[d], w = wr[d];
      acc += x.x * w.x + x.y * w.y + x.z * w.z + x.w * w.w;
    }
    uprime[t * 512 + a] = acc;  // [b][a] row-major
  }
}

// ---------------------------------------------------------------------------
// scores: per block s: rows r = s*64 + b (b = local row 0..63).
//   v[b][a] = sum_d bf16(src[s,b,d]) * W1b[a][d]  via 16x16x32 bf16 MFMA
//   scores[s][b] = b2 + sum_a W2[a]*tanh(v + uprime[b][a])   (mask -> -inf)
// 4 waves; wave w owns cols n = w*128 .. w*128+127 (4 m-frags x 8 n-frags).
// ---------------------------------------------------------------------------
#define LDSTR 40  // LDS row stride in ushorts (32 + 8 pad; keeps 16B align)

__global__ __launch_bounds__(256, 2) void scores_kernel(
    const float* __restrict__ src, const unsigned short* __restrict__ W1b,
    const float* __restrict__ uprime, const float* __restrict__ W2,
    const float* __restrict__ b2, const unsigned char* __restrict__ mask,
    float* __restrict__ scores_g) {
  __shared__ unsigned short A_lds[64 * LDSTR];   // rows x k (bf16)
  __shared__ unsigned short B_lds[512 * LDSTR];  // n x k (bf16)
  __shared__ float s_lds[BATCH];

  const int s = blockIdx.x;
  const int t = threadIdx.x;
  const int w = t >> 6;          // wave 0..3
  const int lane = t & 63;
  const int quad = lane >> 4;    // 0..3
  const int l15 = lane & 15;

  if (t < BATCH) s_lds[t] = 0.f;

  f32x4 acc[4][8];
#pragma unroll
  for (int i = 0; i < 4; ++i)
#pragma unroll
    for (int j = 0; j < 8; ++j) acc[i][j] = (f32x4){0.f, 0.f, 0.f, 0.f};

  const float* srcblk = src + (size_t)s * (BATCH * DDIM);
  const int arow = t >> 2, afi = t & 3;   // A staging: 4 thr/row, 2 f4 each
  const int bnr = t >> 2, bseg = t & 3;   // B staging: rows n=bnr+c*64, 16B segs

  for (int k0 = 0; k0 < DDIM; k0 += 32) {
    // ---- stage A (64 x 32 fp32 -> bf16) ----
    {
      const float4 v0 = *(const float4*)(srcblk + arow * DDIM + k0 + afi * 4);
      const float4 v1 = *(const float4*)(srcblk + arow * DDIM + k0 + 16 + afi * 4);
      ushort4 u0, u1;
      u0.x = f2bf(v0.x); u0.y = f2bf(v0.y); u0.z = f2bf(v0.z); u0.w = f2bf(v0.w);
      u1.x = f2bf(v1.x); u1.y = f2bf(v1.y); u1.z = f2bf(v1.z); u1.w = f2bf(v1.w);
      *(ushort4*)(A_lds + arow * LDSTR + afi * 4) = u0;
      *(ushort4*)(A_lds + arow * LDSTR + 16 + afi * 4) = u1;
    }
    // ---- stage B (512 x 32 bf16) ----
#pragma unroll
    for (int c = 0; c < 8; ++c) {
      const int n = bnr + c * 64;
      u16x8 val = *(const u16x8*)(W1b + n * 512 + k0 + bseg * 8);
      *(u16x8*)(B_lds + n * LDSTR + bseg * 8) = val;
    }
    __syncthreads();

    bf16x8 af[4], bf[8];
#pragma unroll
    for (int i = 0; i < 4; ++i)
      af[i] = *(const bf16x8*)(A_lds + (i * 16 + l15) * LDSTR + quad * 8);
#pragma unroll
    for (int j = 0; j < 8; ++j)
      bf[j] = *(const bf16x8*)(B_lds + (w * 128 + j * 16 + l15) * LDSTR + quad * 8);
#pragma unroll
    for (int i = 0; i < 4; ++i)
#pragma unroll
      for (int j = 0; j < 8; ++j)
        acc[i][j] = __builtin_amdgcn_mfma_f32_16x16x32_bf16(af[i], bf[j], acc[i][j], 0, 0, 0);
    __syncthreads();
  }

  // ---- epilogue: tanh + W2 reduction ----
  float w2r[8];
#pragma unroll
  for (int j = 0; j < 8; ++j) w2r[j] = W2[w * 128 + j * 16 + l15];

#pragma unroll
  for (int i = 0; i < 4; ++i) {
#pragma unroll
    for (int r = 0; r < 4; ++r) {
      const int b = i * 16 + quad * 4 + r;  // D row = local b
      const float* up = uprime + b * 512;
      float sp = 0.f;
#pragma unroll
      for (int j = 0; j < 8; ++j) {
        const int n = w * 128 + j * 16 + l15;  // D col
        sp += w2r[j] * tanhf(acc[i][j][r] + up[n]);
      }
      sp += __shfl_xor(sp, 1);
      sp += __shfl_xor(sp, 2);
      sp += __shfl_xor(sp, 4);
      sp += __shfl_xor(sp, 8);
      if (l15 == 0) atomicAdd(&s_lds[b], sp);
    }
  }
  __syncthreads();
  if (t < BATCH) {
    float sc = s_lds[t] + b2[0];
    if (mask[s * BATCH + t]) sc = -__builtin_inff();
    scores_g[s * BATCH + t] = sc;
  }
}

// ---------------------------------------------------------------------------
// softmax over s for each b. grid: 64 blocks, 256 threads.
// ---------------------------------------------------------------------------
__global__ __launch_bounds__(256) void softmax_kernel(
    const float* __restrict__ scores_g, float* __restrict__ attn_g) {
  __shared__ float red[256];
  const int b = blockIdx.x, t = threadIdx.x;
  float m = -__builtin_inff();
  for (int s = t; s < S_LEN; s += 256) m = fmaxf(m, scores_g[s * BATCH + b]);
  red[t] = m;
  __syncthreads();
  for (int off = 128; off; off >>= 1) {
    if (t < off) red[t] = fmaxf(red[t], red[t + off]);
    __syncthreads();
  }
  m = red[0];
  __syncthreads();
  float sum = 0.f;
  for (int s = t; s < S_LEN; s += 256) sum += __expf(scores_g[s * BATCH + b] - m);
  red[t] = sum;
  __syncthreads();
  for (int off = 128; off; off >>= 1) {
    if (t < off) red[t] += red[t + off];
    __syncthreads();
  }
  const float inv = 1.f / red[0];
  for (int s = t; s < S_LEN; s += 256)
    attn_g[s * BATCH + b] = __expf(scores_g[s * BATCH + b] - m) * inv;
}

// ---------------------------------------------------------------------------
// ctx[b][d] = sum_s attn[s][b] * src[s][b][d]. grid: (16 s-chunks, 64 b).
// ---------------------------------------------------------------------------
__global__ __launch_bounds__(256) void ctx_kernel(
    const float* __restrict__ src, const float* __restrict__ attn_g,
    float* __restrict__ ctx) {
  __shared__ float a_lds[128];
  const int s0 = blockIdx.x * 128, b = blockIdx.y, t = threadIdx.x;
  if (t < 128) a_lds[t] = attn_g[(s0 + t) * BATCH + b];
  __syncthreads();
  float c0 = 0.f, c1 = 0.f;
  for (int i = 0; i < 128; ++i) {
    const float a = a_lds[i];
    const float* p = src + ((size_t)(s0 + i) * BATCH + b) * DDIM;
    c0 += a * p[t];
    c1 += a * p[t + 256];
  }
  atomicAdd(&ctx[b * DDIM + t], c0);
  atomicAdd(&ctx[b * DDIM + t + 256], c1);
}

// ---------------------------------------------------------------------------
extern "C" void kernel_launch(void* const* d_in, const int* in_sizes, int n_in,
                              void* d_out, int out_size, void* d_ws, size_t ws_size,
                              hipStream_t stream) {
  const float* input = (const float*)d_in[0];          // [1,64,512]
  const float* src = (const float*)d_in[1];            // [2048,64,512]
  const unsigned char* mask = (const unsigned char*)d_in[2];  // [2048,64] (all false in test; byte-read safe either way)
  const float* W1 = (const float*)d_in[3];             // [512,1024]
  const float* b1 = (const float*)d_in[4];             // [512]
  const float* W2 = (const float*)d_in[5];             // [1,512]
  const float* b2 = (const float*)d_in[6];             // [1]

  float* ctx = (float*)d_out;                 // [64,512]
  float* attn = (float*)d_out + BATCH * DDIM; // [2048,64]

  unsigned short* W1b = (unsigned short*)d_ws;                        // 512KB bf16 [a][d]
  float* uprime = (float*)((char*)d_ws + 512 * 1024);                 // 128KB [b][a]
  float* scores = (float*)((char*)d_ws + 512 * 1024 + 128 * 1024);    // 512KB [s][b]

  hipMemsetAsync(ctx, 0, BATCH * DDIM * sizeof(float), stream);
  prep_kernel<<<512, 256, 0, stream>>>(W1, b1, input, W1b, uprime);
  scores_kernel<<<S_LEN, 256, 0, stream>>>(src, W1b, uprime, W2, b2, mask, scores);
  softmax_kernel<<<BATCH, 256, 0, stream>>>(scores, attn);
  ctx_kernel<<<dim3(16, BATCH), 256, 0, stream>>>(src, attn, ctx);
}

// Round 2
// 565.473 us; speedup vs baseline: 1.0863x; 1.0863x over previous
//
#include <hip/hip_runtime.h>
#include <hip/hip_bf16.h>
#include <math.h>

// Problem constants (S, B, D_IN, D_SRC, D_ALIGN = 2048, 64, 512, 512, 512)
#define S_LEN 2048
#define BATCH 64
#define DDIM 512

typedef __attribute__((ext_vector_type(8))) short bf16x8;
typedef __attribute__((ext_vector_type(8))) unsigned short u16x8;
typedef __attribute__((ext_vector_type(4))) float f32x4;
typedef __attribute__((ext_vector_type(4))) unsigned int u32x4;

typedef __attribute__((address_space(1))) const void g_void;
typedef __attribute__((address_space(3))) void l_void;

__device__ __forceinline__ unsigned short f2bf(float f) {
  // round-to-nearest-even fp32 -> bf16
  unsigned int u = __float_as_uint(f);
  u += 0x7fffu + ((u >> 16) & 1u);
  return (unsigned short)(u >> 16);
}

__device__ __forceinline__ float tanh_fast(float x) {
  // tanh(x) = 1 - 2/(exp2(2*log2e*x)+1); exact at +-inf, ~1ulp transcendentals
  float e = __builtin_amdgcn_exp2f(x * 2.88539008177793f);
  return 1.0f - 2.0f * __builtin_amdgcn_rcpf(e + 1.0f);
}

// ---------------------------------------------------------------------------
// prep: W1b[a][d] = bf16(W1[a][512+d]);  uprime[b][a] = b1[a] + W1[a,:512].input[b]
// grid: 512 blocks (one per a), 256 threads
// ---------------------------------------------------------------------------
__global__ __launch_bounds__(256) void prep_kernel(
    const float* __restrict__ W1, const float* __restrict__ b1,
    const float* __restrict__ input, unsigned short* __restrict__ W1b,
    float* __restrict__ uprime) {
  __shared__ float w1row[1024];
  const int a = blockIdx.x;
  const int t = threadIdx.x;
  float4 v = *(const float4*)(W1 + a * 1024 + t * 4);
  *(float4*)(w1row + t * 4) = v;
  if (t >= 128) {  // cols 512..1023 -> bf16 B matrix [a][d2]
    ushort4 u;
    u.x = f2bf(v.x); u.y = f2bf(v.y); u.z = f2bf(v.z); u.w = f2bf(v.w);
    *(ushort4*)(W1b + a * 512 + (t * 4 - 512)) = u;
  }
  __syncthreads();
  if (t < BATCH) {
    const float4* inp = (const float4*)(input + t * 512);
    const float4* wr = (const float4*)w1row;
    float acc = b1[a];
#pragma unroll 4
    for (int d = 0; d < 128; ++d) {
      float4 x = inp[d], w = wr[d];
      acc += x.x * w.x + x.y * w.y + x.z * w.z + x.w * w.w;
    }
    uprime[t * 512 + a] = acc;  // [b][a] row-major
  }
}

// ---------------------------------------------------------------------------
// scores v2: per block s (64 rows), N=512, K-slice 32, 16 iters.
// 512 threads = 8 waves; wave w owns cols n = w*64 .. w*64+63 (4x4 frags,
// 64 acc VGPR). Staging: global_load_lds width 16 for BOTH operands.
// A kept fp32 in LDS (32B-chunk rotated layout), cvt->bf16 at frag read.
// B bf16 (16B-chunk rotated layout).
// ---------------------------------------------------------------------------
__global__ __launch_bounds__(512, 3) void scores_kernel(
    const float* __restrict__ src, const unsigned short* __restrict__ W1b,
    const float* __restrict__ uprime, const float* __restrict__ W2,
    const float* __restrict__ b2, const unsigned char* __restrict__ mask,
    float* __restrict__ scores_g) {
  __shared__ float A_lds[64 * 32];            // 8 KB, rotated 32B chunks
  __shared__ unsigned short B_lds[512 * 32];  // 32 KB, rotated 16B chunks
  __shared__ float s_lds[BATCH];

  const int t = threadIdx.x;
  const int s = blockIdx.x;
  const int w = t >> 6;        // wave 0..7 (wave-uniform)
  const int lane = t & 63;
  const int quad = lane >> 4;  // 0..3
  const int l15 = lane & 15;

  if (t < BATCH) s_lds[t] = 0.f;

  f32x4 acc[4][4];
#pragma unroll
  for (int i = 0; i < 4; ++i)
#pragma unroll
    for (int j = 0; j < 4; ++j) acc[i][j] = (f32x4){0.f, 0.f, 0.f, 0.f};

  // ---- staging address setup (loop-invariant) ----
  const float* srcblk = src + (size_t)s * (BATCH * DDIM);
  // A: 1 load/thread. lane -> row ar, 32B chunk p, 16B half h. Physical LDS
  // float index = w*256 + lane*4 = ar*32 + p*8 + h*4. Logical chunk rotated:
  // c_log = (p - ar) & 3, so phys chunk p holds logical k-chunk (p-ar)&3.
  const int ar = w * 8 + (lane >> 3);
  const int ap = (lane >> 1) & 3;
  const int ah = lane & 1;
  const float* gA = srcblk + ar * DDIM + (((ap - ar) & 3) << 3) + (ah << 2);
  // B: 4 loads/thread. lane -> row bn (16/wave), 16B chunk c_phys = lane&3;
  // logical k-chunk = (c_phys - n) & 3.
  const int bn0 = w * 16 + (lane >> 2);
  const int bc = lane & 3;
  const unsigned short* gB0 = W1b + (0 * 128 + bn0) * 512 + (((bc - (0 * 128 + bn0)) & 3) << 3);
  const unsigned short* gB1 = W1b + (1 * 128 + bn0) * 512 + (((bc - (1 * 128 + bn0)) & 3) << 3);
  const unsigned short* gB2 = W1b + (2 * 128 + bn0) * 512 + (((bc - (2 * 128 + bn0)) & 3) << 3);
  const unsigned short* gB3 = W1b + (3 * 128 + bn0) * 512 + (((bc - (3 * 128 + bn0)) & 3) << 3);
  float* ldsA = A_lds + w * 256;                         // wave-uniform base
  unsigned short* ldsB0 = B_lds + (0 * 128 + w * 16) * 32;
  unsigned short* ldsB1 = B_lds + (1 * 128 + w * 16) * 32;
  unsigned short* ldsB2 = B_lds + (2 * 128 + w * 16) * 32;
  unsigned short* ldsB3 = B_lds + (3 * 128 + w * 16) * 32;

  for (int k0 = 0; k0 < DDIM; k0 += 32) {
    __builtin_amdgcn_global_load_lds((g_void*)gA, (l_void*)ldsA, 16, 0, 0);
    __builtin_amdgcn_global_load_lds((g_void*)gB0, (l_void*)ldsB0, 16, 0, 0);
    __builtin_amdgcn_global_load_lds((g_void*)gB1, (l_void*)ldsB1, 16, 0, 0);
    __builtin_amdgcn_global_load_lds((g_void*)gB2, (l_void*)ldsB2, 16, 0, 0);
    __builtin_amdgcn_global_load_lds((g_void*)gB3, (l_void*)ldsB3, 16, 0, 0);
    gA += 32; gB0 += 32; gB1 += 32; gB2 += 32; gB3 += 32;
    __syncthreads();  // compiler drains vmcnt(0) before barrier

    bf16x8 af[4], bfr[4];
#pragma unroll
    for (int i = 0; i < 4; ++i) {
      const int row = i * 16 + l15;
      const float* pa = A_lds + row * 32 + (((quad + row) & 3) << 3);
      const float4 v0 = *(const float4*)pa;
      const float4 v1 = *(const float4*)(pa + 4);
      // fp32 -> bf16 (round-half-up) packed via v_perm
      unsigned x0 = __float_as_uint(v0.x) + 0x8000u;
      unsigned y0 = __float_as_uint(v0.y) + 0x8000u;
      unsigned z0 = __float_as_uint(v0.z) + 0x8000u;
      unsigned w0 = __float_as_uint(v0.w) + 0x8000u;
      unsigned x1 = __float_as_uint(v1.x) + 0x8000u;
      unsigned y1 = __float_as_uint(v1.y) + 0x8000u;
      unsigned z1 = __float_as_uint(v1.z) + 0x8000u;
      unsigned w1 = __float_as_uint(v1.w) + 0x8000u;
      union { u32x4 u; bf16x8 h; } cv;
      cv.u.x = __builtin_amdgcn_perm(y0, x0, 0x07060302u);
      cv.u.y = __builtin_amdgcn_perm(w0, z0, 0x07060302u);
      cv.u.z = __builtin_amdgcn_perm(y1, x1, 0x07060302u);
      cv.u.w = __builtin_amdgcn_perm(w1, z1, 0x07060302u);
      af[i] = cv.h;
    }
#pragma unroll
    for (int j = 0; j < 4; ++j) {
      const int n = w * 64 + j * 16 + l15;
      bfr[j] = *(const bf16x8*)(B_lds + n * 32 + (((quad + n) & 3) << 3));
    }
#pragma unroll
    for (int i = 0; i < 4; ++i)
#pragma unroll
      for (int j = 0; j < 4; ++j)
        acc[i][j] = __builtin_amdgcn_mfma_f32_16x16x32_bf16(af[i], bfr[j], acc[i][j], 0, 0, 0);
    __syncthreads();  // protect LDS before next-iter staging overwrite
  }

  // ---- epilogue: tanh + W2 partial reduction over this wave's 64 cols ----
  float w2r[4];
#pragma unroll
  for (int j = 0; j < 4; ++j) w2r[j] = W2[w * 64 + j * 16 + l15];

#pragma unroll
  for (int i = 0; i < 4; ++i) {
#pragma unroll
    for (int r = 0; r < 4; ++r) {
      const int b = i * 16 + quad * 4 + r;  // D row = local batch index
      const float* up = uprime + b * 512 + w * 64 + l15;
      float sp = 0.f;
#pragma unroll
      for (int j = 0; j < 4; ++j)
        sp += w2r[j] * tanh_fast(acc[i][j][r] + up[j * 16]);
      sp += __shfl_xor(sp, 1);
      sp += __shfl_xor(sp, 2);
      sp += __shfl_xor(sp, 4);
      sp += __shfl_xor(sp, 8);
      if (l15 == 0) atomicAdd(&s_lds[b], sp);
    }
  }
  __syncthreads();
  if (t < BATCH) {
    float sc = s_lds[t] + b2[0];
    if (mask[s * BATCH + t]) sc = -__builtin_inff();
    scores_g[s * BATCH + t] = sc;
  }
}

// ---------------------------------------------------------------------------
// softmax over s for each b. grid: 64 blocks, 256 threads.
// ---------------------------------------------------------------------------
__global__ __launch_bounds__(256) void softmax_kernel(
    const float* __restrict__ scores_g, float* __restrict__ attn_g) {
  __shared__ float red[256];
  const int b = blockIdx.x, t = threadIdx.x;
  float m = -__builtin_inff();
  for (int s = t; s < S_LEN; s += 256) m = fmaxf(m, scores_g[s * BATCH + b]);
  red[t] = m;
  __syncthreads();
  for (int off = 128; off; off >>= 1) {
    if (t < off) red[t] = fmaxf(red[t], red[t + off]);
    __syncthreads();
  }
  m = red[0];
  __syncthreads();
  float sum = 0.f;
  for (int s = t; s < S_LEN; s += 256) sum += __expf(scores_g[s * BATCH + b] - m);
  red[t] = sum;
  __syncthreads();
  for (int off = 128; off; off >>= 1) {
    if (t < off) red[t] += red[t + off];
    __syncthreads();
  }
  const float inv = 1.f / red[0];
  for (int s = t; s < S_LEN; s += 256)
    attn_g[s * BATCH + b] = __expf(scores_g[s * BATCH + b] - m) * inv;
}

// ---------------------------------------------------------------------------
// ctx[b][d] = sum_s attn[s][b] * src[s][b][d]. grid: (16 s-chunks, 64 b).
// ---------------------------------------------------------------------------
__global__ __launch_bounds__(256) void ctx_kernel(
    const float* __restrict__ src, const float* __restrict__ attn_g,
    float* __restrict__ ctx) {
  __shared__ float a_lds[128];
  const int s0 = blockIdx.x * 128, b = blockIdx.y, t = threadIdx.x;
  if (t < 128) a_lds[t] = attn_g[(s0 + t) * BATCH + b];
  __syncthreads();
  float c0 = 0.f, c1 = 0.f;
  for (int i = 0; i < 128; ++i) {
    const float a = a_lds[i];
    const float* p = src + ((size_t)(s0 + i) * BATCH + b) * DDIM;
    c0 += a * p[t];
    c1 += a * p[t + 256];
  }
  atomicAdd(&ctx[b * DDIM + t], c0);
  atomicAdd(&ctx[b * DDIM + t + 256], c1);
}

// ---------------------------------------------------------------------------
extern "C" void kernel_launch(void* const* d_in, const int* in_sizes, int n_in,
                              void* d_out, int out_size, void* d_ws, size_t ws_size,
                              hipStream_t stream) {
  const float* input = (const float*)d_in[0];          // [1,64,512]
  const float* src = (const float*)d_in[1];            // [2048,64,512]
  const unsigned char* mask = (const unsigned char*)d_in[2];  // [2048,64]
  const float* W1 = (const float*)d_in[3];             // [512,1024]
  const float* b1 = (const float*)d_in[4];             // [512]
  const float* W2 = (const float*)d_in[5];             // [1,512]
  const float* b2 = (const float*)d_in[6];             // [1]

  float* ctx = (float*)d_out;                 // [64,512]
  float* attn = (float*)d_out + BATCH * DDIM; // [2048,64]

  unsigned short* W1b = (unsigned short*)d_ws;                        // 512KB bf16 [a][d]
  float* uprime = (float*)((char*)d_ws + 512 * 1024);                 // 128KB [b][a]
  float* scores = (float*)((char*)d_ws + 512 * 1024 + 128 * 1024);    // 512KB [s][b]

  hipMemsetAsync(ctx, 0, BATCH * DDIM * sizeof(float), stream);
  prep_kernel<<<512, 256, 0, stream>>>(W1, b1, input, W1b, uprime);
  scores_kernel<<<S_LEN, 512, 0, stream>>>(src, W1b, uprime, W2, b2, mask, scores);
  softmax_kernel<<<BATCH, 256, 0, stream>>>(scores, attn);
  ctx_kernel<<<dim3(16, BATCH), 256, 0, stream>>>(src, attn, ctx);
}